// Round 8
// baseline (185.099 us; speedup 1.0000x reference)
//
#include <hip/hip_runtime.h>
#include <hip/hip_bf16.h>

// Fused 34->128->128->1 MLP, bf16 MFMA, transposed GEMMs (R7 base).
// R8a: PERMUTED HIDDEN ORDER. Physical hidden h = nq*32 + q*8 + hb*4 + r is
//   assigned to MFMA position (wave nq, col-block hb, quad q, reg r). Then
//   layer-0's C/D fragment IS layer-1's B fragment for kt=nq:
//   - epi0: one ds_write_b128 per pb (16/tile, was 32 b64)
//   - L1: own kt from registers, 48 b128 reads (was 64)
//   - W0 cols / W1 rows+cols / b0 / b1 / W2 all loaded in permuted order;
//     final L2 dot is within-lane so output order is unaffected.
// R8b: DEPTH-2 PREFETCH. emb/x for t+2 and table gathers for t+1 are issued
//   inside tile t's compute; staging-build is pure VALU from registers.
//   (R7 ledger: 2833 cyc/tile wall >> ~1700 pipe work; the gap is the
//   unhidden emb->gather dependent chain at each tile start.)
// Evidence trail: R5 occ 2x -> 0 gain (LDS-bound then); R6 -ds_bpermute
//   115->80; R7 transpose 80->72, conflicts 9M ~ 20% of wall.
// R3 lesson: launch_bounds must exceed liveness (~155 here) -> (256,3)=170.

using bf16x8 = __attribute__((ext_vector_type(8))) short;   // 8 bf16 = 4 VGPRs
using f32x4  = __attribute__((ext_vector_type(4))) float;   // MFMA C/D

#define NPTS    1000000
#define NUMEMB  6572
#define HID     128
#define M_IT    64          // points per block-iteration
#define A0S     72          // A0 row stride in bf16 (144B, 16B-aligned rows)
#define H0S     136         // H0 row stride in bf16 (272B, 16B-aligned rows)
#define TILES   (NPTS / M_IT)   // 15625 exactly
#define NBLOCKS 768         // 3 blocks/CU on 256 CUs

__device__ __forceinline__ unsigned short bf16r(float f) {
    unsigned u;
    __builtin_memcpy(&u, &f, 4);
    u = (u + 0x7fffu + ((u >> 16) & 1u)) >> 16;
    return (unsigned short)u;
}
__device__ __forceinline__ unsigned pk2(float a, float b) {
    // packed RNE f32x2 -> bf16x2 (v_cvt_pk_bf16_f32 on gfx950)
    float2 f2; f2.x = a; f2.y = b;
    __hip_bfloat162 h = __float22bfloat162_rn(f2);
    unsigned u;
    __builtin_memcpy(&u, &h, 4);
    return u;
}
__device__ __forceinline__ float clamp01(float x) {
    return __builtin_amdgcn_fmed3f(x, 0.f, 1.f);
}

__global__ __launch_bounds__(256, 3)
void mlp_fused(const float* __restrict__ x,
               const float* __restrict__ emb,
               const float* __restrict__ em_table,
               const float* __restrict__ W0, const float* __restrict__ b0,
               const float* __restrict__ W1, const float* __restrict__ b1,
               const float* __restrict__ W2, const float* __restrict__ b2,
               float* __restrict__ out)
{
    __shared__ __align__(16) unsigned short A0[M_IT * A0S];  // bf16 [pt][in]
    __shared__ __align__(16) unsigned short H0[M_IT * H0S];  // bf16 [pt][hperm]
    __shared__ __align__(16) float PART[16][M_IT];           // [nq*4+q][pt]

    const int tid  = threadIdx.x;
    const int lane = tid & 63;
    const int nq   = tid >> 6;   // wave's physical hidden block [nq*32,+32)
    const int q    = lane >> 4;  // quad within wave
    const int cl   = lane & 15;
    const int p    = tid >> 2;   // staging: point within tile
    const int s    = tid & 3;    // staging: 8-dim segment of embedding

    // zero A0 once (cols 34..71 stay zero forever; build overwrites 0..33)
    for (int i = tid; i < M_IT * A0S; i += 256) A0[i] = 0;

    // ---- one-time: weight A-fragments (permuted cols) into registers ----
    // A-frag lane (q,cl) holds A[m=cl][k=q*8+e]. Permuted physical hidden
    // for column m within block (nq,hb): h = nq*32 + (m>>2)*8 + hb*4 + (m&3).
    const int hcol = nq * 32 + (cl >> 2) * 8 + (cl & 3);  // + hb*4
    // W0 logical row k: k<32 -> em row 2+k ; k==32 -> x row 0 ; k==33 -> 1.
    bf16x8 w0t[2][2];   // [hb][kt]
    for (int hb = 0; hb < 2; ++hb)
        for (int kt = 0; kt < 2; ++kt) {
            const int col = hcol + hb * 4;
            bf16x8 v;
            #pragma unroll
            for (int e = 0; e < 8; ++e) {
                const int k = kt * 32 + q * 8 + e;
                float val = 0.f;
                if (k < 32)       val = W0[(2 + k) * HID + col];
                else if (k == 32) val = W0[0 * HID + col];
                else if (k == 33) val = W0[1 * HID + col];
                v[e] = (short)bf16r(val);
            }
            w0t[hb][kt] = v;
        }

    // W1: k consumed in PERMUTED physical order kphys = kt*32 + q*8 + e
    // (matches H0/own-frag layout); output cols also permuted.
    bf16x8 w1t[2][4];   // [hb][kt]
    for (int hb = 0; hb < 2; ++hb)
        for (int kt = 0; kt < 4; ++kt) {
            const int col = hcol + hb * 4;
            bf16x8 v;
            #pragma unroll
            for (int e = 0; e < 8; ++e) {
                const int k = kt * 32 + q * 8 + e;
                v[e] = (short)bf16r(W1[k * HID + col]);
            }
            w1t[hb][kt] = v;
        }

    // biases / W2 indexed by this lane's physical h = nq*32 + q*8 + hb*4 + r
    f32x4 b0q[2], b1q[2], w2q[2];
    for (int hb = 0; hb < 2; ++hb)
        for (int r = 0; r < 4; ++r) {
            const int h = nq * 32 + q * 8 + hb * 4 + r;
            b0q[hb][r] = b0[h];
            b1q[hb][r] = b1[h];
            w2q[hb][r] = W2[h];
        }
    const float bias2 = b2[0];

    // ---- prefetch pipeline prologue ----
    int t = blockIdx.x;
    float  feA, feB;
    float2 xvA = {0.f, 0.f}, xvB = {0.f, 0.f};
    float4 gA0, gA1, gA2, gA3;
    {   // fe/x for tile t, then its gathers (one-time stall)
        const int gp = t * M_IT + p;
        feA = emb[gp];
        if (s == 0) xvA = *(const float2*)(x + 2 * gp);
        const int e1 = (int)feA;
        const int e2 = (e1 + 1 < NUMEMB) ? e1 + 1 : NUMEMB - 1;
        const float4* p1 = (const float4*)(em_table + e1 * 32 + s * 8);
        const float4* p2 = (const float4*)(em_table + e2 * 32 + s * 8);
        gA0 = p1[0]; gA1 = p1[1]; gA2 = p2[0]; gA3 = p2[1];
    }
    {   // fe/x for tile t+1
        int t1 = t + gridDim.x; if (t1 >= TILES) t1 = t;
        const int gp = t1 * M_IT + p;
        feB = emb[gp];
        if (s == 0) xvB = *(const float2*)(x + 2 * gp);
    }

    __syncthreads();   // A0 zeroing visible before first build

    for (; t < TILES; t += gridDim.x) {
        const int base = t * M_IT;

        // ---- stage A0 from prefetched registers (pure VALU) ----
        {
            const float r = feA - (float)(int)feA;
            uint4 d;
            d.x = pk2(gA0.x + (gA2.x - gA0.x) * r, gA0.y + (gA2.y - gA0.y) * r);
            d.y = pk2(gA0.z + (gA2.z - gA0.z) * r, gA0.w + (gA2.w - gA0.w) * r);
            d.z = pk2(gA1.x + (gA3.x - gA1.x) * r, gA1.y + (gA3.y - gA1.y) * r);
            d.w = pk2(gA1.z + (gA3.z - gA1.z) * r, gA1.w + (gA3.w - gA1.w) * r);
            *(uint4*)&A0[p * A0S + s * 8] = d;
            if (s == 0) *(unsigned*)&A0[p * A0S + 32] = pk2(xvA.x, xvA.y);
        }
        __syncthreads();

        // ---- layer 0 (transposed, permuted cols): bias in acc ----
        f32x4 acc[4][2];   // [pb][hb]
        #pragma unroll
        for (int pb = 0; pb < 4; ++pb)
            #pragma unroll
            for (int hb = 0; hb < 2; ++hb)
                acc[pb][hb] = b0q[hb];
        #pragma unroll
        for (int pb = 0; pb < 4; ++pb) {
            #pragma unroll
            for (int kt = 0; kt < 2; ++kt) {
                bf16x8 bfrag = *(const bf16x8*)
                    &A0[(pb * 16 + cl) * A0S + kt * 32 + q * 8];
                #pragma unroll
                for (int hb = 0; hb < 2; ++hb)
                    acc[pb][hb] = __builtin_amdgcn_mfma_f32_16x16x32_bf16(
                        w0t[hb][kt], bfrag, acc[pb][hb], 0, 0, 0);
            }
        }
        // epi0: lane's 8 permuted hiddens == L1 B-frag for kt=nq.
        // One b128 to H0 (for the other 3 waves) + keep in registers.
        uint4 own[4];
        #pragma unroll
        for (int pb = 0; pb < 4; ++pb) {
            const f32x4 v0 = acc[pb][0], v1 = acc[pb][1];
            uint4 w;
            w.x = pk2(clamp01(v0[0]), clamp01(v0[1]));
            w.y = pk2(clamp01(v0[2]), clamp01(v0[3]));
            w.z = pk2(clamp01(v1[0]), clamp01(v1[1]));
            w.w = pk2(clamp01(v1[2]), clamp01(v1[3]));
            own[pb] = w;
            *(uint4*)&H0[(pb * 16 + cl) * H0S + nq * 32 + q * 8] = w;
        }
        __syncthreads();

        // ---- layer 1 (transposed, permuted k and cols) ----
        #pragma unroll
        for (int pb = 0; pb < 4; ++pb)
            #pragma unroll
            for (int hb = 0; hb < 2; ++hb)
                acc[pb][hb] = b1q[hb];
        #pragma unroll
        for (int pb = 0; pb < 4; ++pb) {
            #pragma unroll
            for (int kt = 0; kt < 4; ++kt) {
                bf16x8 bfrag;
                if (kt == nq) {
                    __builtin_memcpy(&bfrag, &own[pb], 16);
                } else {
                    bfrag = *(const bf16x8*)
                        &H0[(pb * 16 + cl) * H0S + kt * 32 + q * 8];
                }
                #pragma unroll
                for (int hb = 0; hb < 2; ++hb)
                    acc[pb][hb] = __builtin_amdgcn_mfma_f32_16x16x32_bf16(
                        w1t[hb][kt], bfrag, acc[pb][hb], 0, 0, 0);
            }
        }

        // ---- prefetch: gathers for t+1 (feB ready), fe/x for t+2 ----
        float4 nB0, nB1, nB2, nB3;
        {
            const int e1 = (int)feB;
            const int e2 = (e1 + 1 < NUMEMB) ? e1 + 1 : NUMEMB - 1;
            const float4* p1 = (const float4*)(em_table + e1 * 32 + s * 8);
            const float4* p2 = (const float4*)(em_table + e2 * 32 + s * 8);
            nB0 = p1[0]; nB1 = p1[1]; nB2 = p2[0]; nB3 = p2[1];
        }
        float feC; float2 xvC = {0.f, 0.f};
        {
            int t2 = t + 2 * (int)gridDim.x; if (t2 >= TILES) t2 = t;
            const int gp = t2 * M_IT + p;
            feC = emb[gp];
            if (s == 0) xvC = *(const float2*)(x + 2 * gp);
        }

        // ---- epi1 + layer 2: within-lane dot over lane's 8 physical h2 ----
        #pragma unroll
        for (int pb = 0; pb < 4; ++pb) {
            float sum = 0.f;
            #pragma unroll
            for (int hb = 0; hb < 2; ++hb) {
                const f32x4 v = acc[pb][hb];
                sum += clamp01(v[0]) * w2q[hb][0];
                sum += clamp01(v[1]) * w2q[hb][1];
                sum += clamp01(v[2]) * w2q[hb][2];
                sum += clamp01(v[3]) * w2q[hb][3];
            }
            PART[nq * 4 + q][pb * 16 + cl] = sum;
        }
        __syncthreads();

        if (tid < 64) {
            float z = bias2;
            #pragma unroll
            for (int i = 0; i < 16; ++i) z += PART[i][tid];
            out[base + tid] = 1.f / (1.f + __expf(-z));
        }

        // rotate prefetch pipeline
        feA = feB; xvA = xvB; gA0 = nB0; gA1 = nB1; gA2 = nB2; gA3 = nB3;
        feB = feC; xvB = xvC;
        // hazards: A0 rewrite at loop top is >=1 barrier after its last read
        // (L0 of this tile); H0 write (next epi0) is 2 barriers after L1
        // reads; PART rewrite is 2 barriers after out-read.
    }
}

extern "C" void kernel_launch(void* const* d_in, const int* in_sizes, int n_in,
                              void* d_out, int out_size, void* d_ws, size_t ws_size,
                              hipStream_t stream) {
    const float* x   = (const float*)d_in[0];
    const float* emb = (const float*)d_in[1];
    const float* emt = (const float*)d_in[2];
    const float* W0  = (const float*)d_in[3];
    const float* b0  = (const float*)d_in[4];
    const float* W1  = (const float*)d_in[5];
    const float* b1  = (const float*)d_in[6];
    const float* W2  = (const float*)d_in[7];
    const float* b2  = (const float*)d_in[8];
    mlp_fused<<<NBLOCKS, 256, 0, stream>>>(x, emb, emt, W0, b0, W1, b1, W2, b2,
                                           (float*)d_out);
}

// Round 9
// 174.259 us; speedup vs baseline: 1.0622x; 1.0622x over previous
//
#include <hip/hip_runtime.h>
#include <hip/hip_bf16.h>

// Fused 34->128->128->1 MLP, bf16 MFMA, transposed GEMMs (R7 base).
// R9 = R7 + R8a (permuted hidden + own-frag forwarding) + 3-reg fe/x
// prefetch. R8's depth-2 gather pipeline held ~22 VGPRs live across both
// MFMA sections -> allocator spilled (WRITE_SIZE 3.9MB->199MB, 128us).
// Gathers now load-and-use at tile top (no long liveness).
// R8a recap: physical hidden h = nq*32 + q*8 + hb*4 + r at MFMA position
// (nq,hb,q,r) makes L0's C/D frag == L1's B frag for kt=nq:
//   epi0 16 ds_write_b128 (was 32 b64), L1 48 b128 reads (was 64),
//   W0/W1/b0/b1/W2 loaded in permuted order; L2 dot within-lane.
// Evidence: R5 occ 2x->0 gain; R6 -ds_bpermute 115->80; R7 transpose
// 80->72; R8 spill lesson. LDS-pipe issue remains the limiting resource.

using bf16x8 = __attribute__((ext_vector_type(8))) short;   // 8 bf16 = 4 VGPRs
using f32x4  = __attribute__((ext_vector_type(4))) float;   // MFMA C/D

#define NPTS    1000000
#define NUMEMB  6572
#define HID     128
#define M_IT    64          // points per block-iteration
#define A0S     72          // A0 row stride in bf16 (144B, 16B-aligned rows)
#define H0S     136         // H0 row stride in bf16 (272B, 16B-aligned rows)
#define TILES   (NPTS / M_IT)   // 15625 exactly
#define NBLOCKS 768         // 3 blocks/CU on 256 CUs

__device__ __forceinline__ unsigned short bf16r(float f) {
    unsigned u;
    __builtin_memcpy(&u, &f, 4);
    u = (u + 0x7fffu + ((u >> 16) & 1u)) >> 16;
    return (unsigned short)u;
}
__device__ __forceinline__ unsigned pk2(float a, float b) {
    // packed RNE f32x2 -> bf16x2 (v_cvt_pk_bf16_f32 on gfx950)
    float2 f2; f2.x = a; f2.y = b;
    __hip_bfloat162 h = __float22bfloat162_rn(f2);
    unsigned u;
    __builtin_memcpy(&u, &h, 4);
    return u;
}
__device__ __forceinline__ float clamp01(float x) {
    return __builtin_amdgcn_fmed3f(x, 0.f, 1.f);
}

__global__ __launch_bounds__(256, 3)
void mlp_fused(const float* __restrict__ x,
               const float* __restrict__ emb,
               const float* __restrict__ em_table,
               const float* __restrict__ W0, const float* __restrict__ b0,
               const float* __restrict__ W1, const float* __restrict__ b1,
               const float* __restrict__ W2, const float* __restrict__ b2,
               float* __restrict__ out)
{
    __shared__ __align__(16) unsigned short A0[M_IT * A0S];  // bf16 [pt][in]
    __shared__ __align__(16) unsigned short H0[M_IT * H0S];  // bf16 [pt][hperm]
    __shared__ __align__(16) float PART[16][M_IT];           // [nq*4+q][pt]

    const int tid  = threadIdx.x;
    const int lane = tid & 63;
    const int nq   = tid >> 6;   // wave's physical hidden block [nq*32,+32)
    const int q    = lane >> 4;  // quad within wave
    const int cl   = lane & 15;
    const int p    = tid >> 2;   // staging: point within tile
    const int s    = tid & 3;    // staging: 8-dim segment of embedding

    // zero A0 once (cols 34..71 stay zero forever; build overwrites 0..33)
    for (int i = tid; i < M_IT * A0S; i += 256) A0[i] = 0;

    // ---- one-time: weight A-fragments (permuted cols) into registers ----
    // A-frag lane (q,cl) holds A[m=cl][k=q*8+e]. Permuted physical hidden
    // for column m within block (nq,hb): h = nq*32 + (m>>2)*8 + hb*4 + (m&3).
    const int hcol = nq * 32 + (cl >> 2) * 8 + (cl & 3);  // + hb*4
    // W0 logical row k: k<32 -> em row 2+k ; k==32 -> x row 0 ; k==33 -> 1.
    bf16x8 w0t[2][2];   // [hb][kt]
    for (int hb = 0; hb < 2; ++hb)
        for (int kt = 0; kt < 2; ++kt) {
            const int col = hcol + hb * 4;
            bf16x8 v;
            #pragma unroll
            for (int e = 0; e < 8; ++e) {
                const int k = kt * 32 + q * 8 + e;
                float val = 0.f;
                if (k < 32)       val = W0[(2 + k) * HID + col];
                else if (k == 32) val = W0[0 * HID + col];
                else if (k == 33) val = W0[1 * HID + col];
                v[e] = (short)bf16r(val);
            }
            w0t[hb][kt] = v;
        }

    // W1: k consumed in PERMUTED physical order kphys = kt*32 + q*8 + e
    // (matches H0/own-frag layout); output cols also permuted.
    bf16x8 w1t[2][4];   // [hb][kt]
    for (int hb = 0; hb < 2; ++hb)
        for (int kt = 0; kt < 4; ++kt) {
            const int col = hcol + hb * 4;
            bf16x8 v;
            #pragma unroll
            for (int e = 0; e < 8; ++e) {
                const int k = kt * 32 + q * 8 + e;
                v[e] = (short)bf16r(W1[k * HID + col]);
            }
            w1t[hb][kt] = v;
        }

    // biases / W2 indexed by this lane's physical h = nq*32 + q*8 + hb*4 + r
    f32x4 b0q[2], b1q[2], w2q[2];
    for (int hb = 0; hb < 2; ++hb)
        for (int r = 0; r < 4; ++r) {
            const int h = nq * 32 + q * 8 + hb * 4 + r;
            b0q[hb][r] = b0[h];
            b1q[hb][r] = b1[h];
            w2q[hb][r] = W2[h];
        }
    const float bias2 = b2[0];

    // ---- shallow prefetch: fe/x for the first tile (3 regs) ----
    int t = blockIdx.x;
    float  feA;
    float2 xvA = {0.f, 0.f};
    {
        const int gp = t * M_IT + p;
        feA = emb[gp];
        if (s == 0) xvA = *(const float2*)(x + 2 * gp);
    }

    __syncthreads();   // A0 zeroing visible before first build

    for (; t < TILES; t += gridDim.x) {
        const int base = t * M_IT;

        // ---- stage inputs into A0 (gathers start immediately: feA ready) --
        {
            const int e1 = (int)feA;
            const int e2 = (e1 + 1 < NUMEMB) ? e1 + 1 : NUMEMB - 1;
            const float r = feA - (float)e1;
            const float4* p1 = (const float4*)(em_table + e1 * 32 + s * 8);
            const float4* p2 = (const float4*)(em_table + e2 * 32 + s * 8);
            const float4 a0v = p1[0], a1v = p1[1];
            const float4 c0v = p2[0], c1v = p2[1];
            uint4 d;
            d.x = pk2(a0v.x + (c0v.x - a0v.x) * r, a0v.y + (c0v.y - a0v.y) * r);
            d.y = pk2(a0v.z + (c0v.z - a0v.z) * r, a0v.w + (c0v.w - a0v.w) * r);
            d.z = pk2(a1v.x + (c1v.x - a1v.x) * r, a1v.y + (c1v.y - a1v.y) * r);
            d.w = pk2(a1v.z + (c1v.z - a1v.z) * r, a1v.w + (c1v.w - a1v.w) * r);
            *(uint4*)&A0[p * A0S + s * 8] = d;
            if (s == 0) *(unsigned*)&A0[p * A0S + 32] = pk2(xvA.x, xvA.y);
        }
        __syncthreads();

        // ---- layer 0 (transposed, permuted cols): bias in acc ----
        f32x4 acc[4][2];   // [pb][hb]
        #pragma unroll
        for (int pb = 0; pb < 4; ++pb)
            #pragma unroll
            for (int hb = 0; hb < 2; ++hb)
                acc[pb][hb] = b0q[hb];
        #pragma unroll
        for (int pb = 0; pb < 4; ++pb) {
            #pragma unroll
            for (int kt = 0; kt < 2; ++kt) {
                bf16x8 bfrag = *(const bf16x8*)
                    &A0[(pb * 16 + cl) * A0S + kt * 32 + q * 8];
                #pragma unroll
                for (int hb = 0; hb < 2; ++hb)
                    acc[pb][hb] = __builtin_amdgcn_mfma_f32_16x16x32_bf16(
                        w0t[hb][kt], bfrag, acc[pb][hb], 0, 0, 0);
            }
        }

        // prefetch fe/x for next tile (3 regs live across L1 only)
        {
            int t1 = t + gridDim.x; if (t1 >= TILES) t1 = t;
            const int gp = t1 * M_IT + p;
            feA = emb[gp];
            if (s == 0) xvA = *(const float2*)(x + 2 * gp);
        }

        // epi0: lane's 8 permuted hiddens == L1 B-frag for kt=nq.
        // One b128 to H0 (for the other 3 waves) + keep in registers.
        uint4 own[4];
        #pragma unroll
        for (int pb = 0; pb < 4; ++pb) {
            const f32x4 v0 = acc[pb][0], v1 = acc[pb][1];
            uint4 w;
            w.x = pk2(clamp01(v0[0]), clamp01(v0[1]));
            w.y = pk2(clamp01(v0[2]), clamp01(v0[3]));
            w.z = pk2(clamp01(v1[0]), clamp01(v1[1]));
            w.w = pk2(clamp01(v1[2]), clamp01(v1[3]));
            own[pb] = w;
            *(uint4*)&H0[(pb * 16 + cl) * H0S + nq * 32 + q * 8] = w;
        }
        __syncthreads();

        // ---- layer 1 (transposed, permuted k and cols) ----
        #pragma unroll
        for (int pb = 0; pb < 4; ++pb)
            #pragma unroll
            for (int hb = 0; hb < 2; ++hb)
                acc[pb][hb] = b1q[hb];
        #pragma unroll
        for (int pb = 0; pb < 4; ++pb) {
            #pragma unroll
            for (int kt = 0; kt < 4; ++kt) {
                bf16x8 bfrag;
                if (kt == nq) {
                    __builtin_memcpy(&bfrag, &own[pb], 16);
                } else {
                    bfrag = *(const bf16x8*)
                        &H0[(pb * 16 + cl) * H0S + kt * 32 + q * 8];
                }
                #pragma unroll
                for (int hb = 0; hb < 2; ++hb)
                    acc[pb][hb] = __builtin_amdgcn_mfma_f32_16x16x32_bf16(
                        w1t[hb][kt], bfrag, acc[pb][hb], 0, 0, 0);
            }
        }

        // ---- epi1 + layer 2: within-lane dot over lane's 8 physical h2 ----
        #pragma unroll
        for (int pb = 0; pb < 4; ++pb) {
            float sum = 0.f;
            #pragma unroll
            for (int hb = 0; hb < 2; ++hb) {
                const f32x4 v = acc[pb][hb];
                sum += clamp01(v[0]) * w2q[hb][0];
                sum += clamp01(v[1]) * w2q[hb][1];
                sum += clamp01(v[2]) * w2q[hb][2];
                sum += clamp01(v[3]) * w2q[hb][3];
            }
            PART[nq * 4 + q][pb * 16 + cl] = sum;
        }
        __syncthreads();

        if (tid < 64) {
            float z = bias2;
            #pragma unroll
            for (int i = 0; i < 16; ++i) z += PART[i][tid];
            out[base + tid] = 1.f / (1.f + __expf(-z));
        }
        // hazards: A0 rewrite (next loop top) >=1 barrier after L0 reads;
        // H0 rewrite 2 barriers after L1 reads; PART rewrite 2 barriers
        // after the out-read.
    }
}

extern "C" void kernel_launch(void* const* d_in, const int* in_sizes, int n_in,
                              void* d_out, int out_size, void* d_ws, size_t ws_size,
                              hipStream_t stream) {
    const float* x   = (const float*)d_in[0];
    const float* emb = (const float*)d_in[1];
    const float* emt = (const float*)d_in[2];
    const float* W0  = (const float*)d_in[3];
    const float* b0  = (const float*)d_in[4];
    const float* W1  = (const float*)d_in[5];
    const float* b1  = (const float*)d_in[6];
    const float* W2  = (const float*)d_in[7];
    const float* b2  = (const float*)d_in[8];
    mlp_fused<<<NBLOCKS, 256, 0, stream>>>(x, emb, emt, W0, b0, W1, b1, W2, b2,
                                           (float*)d_out);
}

// Round 10
// 126.479 us; speedup vs baseline: 1.4635x; 1.3778x over previous
//
#include <hip/hip_runtime.h>
#include <hip/hip_bf16.h>

// Fused 34->128->128->1 MLP, bf16 MFMA, transposed GEMMs (R7 base).
// R10 = R9 with ROTATED W1 fragments to kill the spill R9 still had
// (WRITE_SIZE 124MB: own[] stayed conditionally-live through all of L1
// because the kt==nq consumer test is runtime). w1r[hb][kk] holds W1 rows
// for physical kt=(nq+kk)&3, so L1 iterates kk=0..3 with LITERAL register
// indices: kk=0 consumes own[] (dead right after), kk>=1 read H0 at
// runtime-computed addresses (addr math only, no dynamic reg indexing).
// Peak liveness ~130 < budget 168 at (256,3).
// R8a recap (kept): physical hidden h = nq*32 + q*8 + hb*4 + r at MFMA
// position (nq,hb,q,r) makes L0's C/D frag == L1's B frag for kt=nq:
//   epi0 16 ds_write_b128, L1 48 b128 reads, weights loaded permuted,
//   L2 dot within-lane. ~136 DS wave-instrs/tile.
// Evidence: R5 occ 2x->0 gain; R6 -ds_bpermute 115->80; R7 transpose
// 80->72; R8/R9 spill lessons (WRITE_SIZE is the spill tell).

using bf16x8 = __attribute__((ext_vector_type(8))) short;   // 8 bf16 = 4 VGPRs
using f32x4  = __attribute__((ext_vector_type(4))) float;   // MFMA C/D

#define NPTS    1000000
#define NUMEMB  6572
#define HID     128
#define M_IT    64          // points per block-iteration
#define A0S     72          // A0 row stride in bf16 (144B, 16B-aligned rows)
#define H0S     136         // H0 row stride in bf16 (272B, 16B-aligned rows)
#define TILES   (NPTS / M_IT)   // 15625 exactly
#define NBLOCKS 768         // 3 blocks/CU on 256 CUs

__device__ __forceinline__ unsigned short bf16r(float f) {
    unsigned u;
    __builtin_memcpy(&u, &f, 4);
    u = (u + 0x7fffu + ((u >> 16) & 1u)) >> 16;
    return (unsigned short)u;
}
__device__ __forceinline__ unsigned pk2(float a, float b) {
    // packed RNE f32x2 -> bf16x2 (v_cvt_pk_bf16_f32 on gfx950)
    float2 f2; f2.x = a; f2.y = b;
    __hip_bfloat162 h = __float22bfloat162_rn(f2);
    unsigned u;
    __builtin_memcpy(&u, &h, 4);
    return u;
}
__device__ __forceinline__ float clamp01(float x) {
    return __builtin_amdgcn_fmed3f(x, 0.f, 1.f);
}

__global__ __launch_bounds__(256, 3)
void mlp_fused(const float* __restrict__ x,
               const float* __restrict__ emb,
               const float* __restrict__ em_table,
               const float* __restrict__ W0, const float* __restrict__ b0,
               const float* __restrict__ W1, const float* __restrict__ b1,
               const float* __restrict__ W2, const float* __restrict__ b2,
               float* __restrict__ out)
{
    __shared__ __align__(16) unsigned short A0[M_IT * A0S];  // bf16 [pt][in]
    __shared__ __align__(16) unsigned short H0[M_IT * H0S];  // bf16 [pt][hperm]
    __shared__ __align__(16) float PART[16][M_IT];           // [nq*4+q][pt]

    const int tid  = threadIdx.x;
    const int lane = tid & 63;
    const int nq   = tid >> 6;   // wave's physical hidden block [nq*32,+32)
    const int q    = lane >> 4;  // quad within wave
    const int cl   = lane & 15;
    const int p    = tid >> 2;   // staging: point within tile
    const int s    = tid & 3;    // staging: 8-dim segment of embedding

    // zero A0 once (cols 34..71 stay zero forever; build overwrites 0..33)
    for (int i = tid; i < M_IT * A0S; i += 256) A0[i] = 0;

    // ---- one-time: weight A-fragments (permuted cols) into registers ----
    // A-frag lane (q,cl) holds A[m=cl][k=q*8+e]. Permuted physical hidden
    // for column m within block (nq,hb): h = nq*32 + (m>>2)*8 + hb*4 + (m&3).
    const int hcol = nq * 32 + (cl >> 2) * 8 + (cl & 3);  // + hb*4
    // W0 logical row k: k<32 -> em row 2+k ; k==32 -> x row 0 ; k==33 -> 1.
    bf16x8 w0t[2][2];   // [hb][kt]
    for (int hb = 0; hb < 2; ++hb)
        for (int kt = 0; kt < 2; ++kt) {
            const int col = hcol + hb * 4;
            bf16x8 v;
            #pragma unroll
            for (int e = 0; e < 8; ++e) {
                const int k = kt * 32 + q * 8 + e;
                float val = 0.f;
                if (k < 32)       val = W0[(2 + k) * HID + col];
                else if (k == 32) val = W0[0 * HID + col];
                else if (k == 33) val = W0[1 * HID + col];
                v[e] = (short)bf16r(val);
            }
            w0t[hb][kt] = v;
        }

    // W1 ROTATED: w1r[hb][kk] holds rows kphys = ((nq+kk)&3)*32 + q*8 + e
    // (permuted k order matches H0/own-frag layout); cols permuted too.
    bf16x8 w1r[2][4];   // [hb][kk]
    for (int hb = 0; hb < 2; ++hb)
        for (int kk = 0; kk < 4; ++kk) {
            const int kt  = (nq + kk) & 3;
            const int col = hcol + hb * 4;
            bf16x8 v;
            #pragma unroll
            for (int e = 0; e < 8; ++e) {
                const int k = kt * 32 + q * 8 + e;
                v[e] = (short)bf16r(W1[k * HID + col]);
            }
            w1r[hb][kk] = v;
        }

    // biases / W2 indexed by this lane's physical h = nq*32 + q*8 + hb*4 + r
    f32x4 b0q[2], b1q[2], w2q[2];
    for (int hb = 0; hb < 2; ++hb)
        for (int r = 0; r < 4; ++r) {
            const int h = nq * 32 + q * 8 + hb * 4 + r;
            b0q[hb][r] = b0[h];
            b1q[hb][r] = b1[h];
            w2q[hb][r] = W2[h];
        }
    const float bias2 = b2[0];

    // ---- shallow prefetch: fe/x for the first tile (3 regs) ----
    int t = blockIdx.x;
    float  feA;
    float2 xvA = {0.f, 0.f};
    {
        const int gp = t * M_IT + p;
        feA = emb[gp];
        if (s == 0) xvA = *(const float2*)(x + 2 * gp);
    }

    __syncthreads();   // A0 zeroing visible before first build

    for (; t < TILES; t += gridDim.x) {
        const int base = t * M_IT;

        // ---- stage inputs into A0 (gathers start immediately: feA ready) --
        {
            const int e1 = (int)feA;
            const int e2 = (e1 + 1 < NUMEMB) ? e1 + 1 : NUMEMB - 1;
            const float r = feA - (float)e1;
            const float4* p1 = (const float4*)(em_table + e1 * 32 + s * 8);
            const float4* p2 = (const float4*)(em_table + e2 * 32 + s * 8);
            const float4 a0v = p1[0], a1v = p1[1];
            const float4 c0v = p2[0], c1v = p2[1];
            uint4 d;
            d.x = pk2(a0v.x + (c0v.x - a0v.x) * r, a0v.y + (c0v.y - a0v.y) * r);
            d.y = pk2(a0v.z + (c0v.z - a0v.z) * r, a0v.w + (c0v.w - a0v.w) * r);
            d.z = pk2(a1v.x + (c1v.x - a1v.x) * r, a1v.y + (c1v.y - a1v.y) * r);
            d.w = pk2(a1v.z + (c1v.z - a1v.z) * r, a1v.w + (c1v.w - a1v.w) * r);
            *(uint4*)&A0[p * A0S + s * 8] = d;
            if (s == 0) *(unsigned*)&A0[p * A0S + 32] = pk2(xvA.x, xvA.y);
        }
        __syncthreads();

        // ---- layer 0 (transposed, permuted cols): bias in acc ----
        f32x4 acc[4][2];   // [pb][hb]
        #pragma unroll
        for (int pb = 0; pb < 4; ++pb)
            #pragma unroll
            for (int hb = 0; hb < 2; ++hb)
                acc[pb][hb] = b0q[hb];
        #pragma unroll
        for (int pb = 0; pb < 4; ++pb) {
            #pragma unroll
            for (int kt = 0; kt < 2; ++kt) {
                bf16x8 bfrag = *(const bf16x8*)
                    &A0[(pb * 16 + cl) * A0S + kt * 32 + q * 8];
                #pragma unroll
                for (int hb = 0; hb < 2; ++hb)
                    acc[pb][hb] = __builtin_amdgcn_mfma_f32_16x16x32_bf16(
                        w0t[hb][kt], bfrag, acc[pb][hb], 0, 0, 0);
            }
        }

        // prefetch fe/x for next tile (3 regs live across L1 only)
        {
            int t1 = t + gridDim.x; if (t1 >= TILES) t1 = t;
            const int gp = t1 * M_IT + p;
            feA = emb[gp];
            if (s == 0) xvA = *(const float2*)(x + 2 * gp);
        }

        // epi0: lane's 8 permuted hiddens == L1 B-frag for kt=nq.
        // One b128 to H0 (for the other 3 waves) + keep in registers.
        uint4 own[4];
        #pragma unroll
        for (int pb = 0; pb < 4; ++pb) {
            const f32x4 v0 = acc[pb][0], v1 = acc[pb][1];
            uint4 w;
            w.x = pk2(clamp01(v0[0]), clamp01(v0[1]));
            w.y = pk2(clamp01(v0[2]), clamp01(v0[3]));
            w.z = pk2(clamp01(v1[0]), clamp01(v1[1]));
            w.w = pk2(clamp01(v1[2]), clamp01(v1[3]));
            own[pb] = w;
            *(uint4*)&H0[(pb * 16 + cl) * H0S + nq * 32 + q * 8] = w;
        }
        __syncthreads();

        // ---- layer 1: kk=0 consumes own[] (then dead); kk>=1 from LDS ----
        #pragma unroll
        for (int pb = 0; pb < 4; ++pb)
            #pragma unroll
            for (int hb = 0; hb < 2; ++hb)
                acc[pb][hb] = b1q[hb];
        #pragma unroll
        for (int pb = 0; pb < 4; ++pb) {
            bf16x8 bfrag;
            __builtin_memcpy(&bfrag, &own[pb], 16);
            #pragma unroll
            for (int hb = 0; hb < 2; ++hb)
                acc[pb][hb] = __builtin_amdgcn_mfma_f32_16x16x32_bf16(
                    w1r[hb][0], bfrag, acc[pb][hb], 0, 0, 0);
        }
        #pragma unroll
        for (int kk = 1; kk < 4; ++kk) {
            const int kcol = (((nq + kk) & 3) << 5) + q * 8;  // runtime addr
            #pragma unroll
            for (int pb = 0; pb < 4; ++pb) {
                bf16x8 bfrag = *(const bf16x8*)
                    &H0[(pb * 16 + cl) * H0S + kcol];
                #pragma unroll
                for (int hb = 0; hb < 2; ++hb)
                    acc[pb][hb] = __builtin_amdgcn_mfma_f32_16x16x32_bf16(
                        w1r[hb][kk], bfrag, acc[pb][hb], 0, 0, 0);
            }
        }

        // ---- epi1 + layer 2: within-lane dot over lane's 8 physical h2 ----
        #pragma unroll
        for (int pb = 0; pb < 4; ++pb) {
            float sum = 0.f;
            #pragma unroll
            for (int hb = 0; hb < 2; ++hb) {
                const f32x4 v = acc[pb][hb];
                sum += clamp01(v[0]) * w2q[hb][0];
                sum += clamp01(v[1]) * w2q[hb][1];
                sum += clamp01(v[2]) * w2q[hb][2];
                sum += clamp01(v[3]) * w2q[hb][3];
            }
            PART[nq * 4 + q][pb * 16 + cl] = sum;
        }
        __syncthreads();

        if (tid < 64) {
            float z = bias2;
            #pragma unroll
            for (int i = 0; i < 16; ++i) z += PART[i][tid];
            out[base + tid] = 1.f / (1.f + __expf(-z));
        }
        // hazards: A0 rewrite (next loop top) >=1 barrier after L0 reads;
        // H0 rewrite 2 barriers after L1 reads; PART rewrite 2 barriers
        // after the out-read.
    }
}

extern "C" void kernel_launch(void* const* d_in, const int* in_sizes, int n_in,
                              void* d_out, int out_size, void* d_ws, size_t ws_size,
                              hipStream_t stream) {
    const float* x   = (const float*)d_in[0];
    const float* emb = (const float*)d_in[1];
    const float* emt = (const float*)d_in[2];
    const float* W0  = (const float*)d_in[3];
    const float* b0  = (const float*)d_in[4];
    const float* W1  = (const float*)d_in[5];
    const float* b1  = (const float*)d_in[6];
    const float* W2  = (const float*)d_in[7];
    const float* b2  = (const float*)d_in[8];
    mlp_fused<<<NBLOCKS, 256, 0, stream>>>(x, emb, emt, W0, b0, W1, b1, W2, b2,
                                           (float*)d_out);
}